// Round 4
// baseline (131.587 us; speedup 1.0000x reference)
//
#include <hip/hip_runtime.h>

#define HSZ 128
#define ISZ 28
#define TSZ 28
#define CSZ 10
#define BT  32     // batch rows per block: 2 MFMA col-groups of 16
#define NG  2
#define NT  512    // waves 0-3: layer-0 producers; waves 4-7: layer-1 consumers

typedef _Float16 half_t;
typedef _Float16 v8h __attribute__((ext_vector_type(8)));
typedef _Float16 v4h __attribute__((ext_vector_type(4)));
typedef float v4f __attribute__((ext_vector_type(4)));

__device__ __forceinline__ float fast_tanh(float x) {
    // 1 - 2/(e^{2x}+1); saturates correctly (+-inf -> +-1)
    float e = __expf(2.f * x);
    return 1.f - 2.f * __builtin_amdgcn_rcpf(e + 1.f);
}

__device__ __forceinline__ int imin(int a, int b) { return a < b ? a : b; }

// MFMA 16x16x32 f16 layouts (HW-verified, carried from round-2 kernel):
//   A-frag: lane holds A[m = lane&15][k = (lane>>4)*8 + j], j=0..7
//   B-frag: lane holds B[k = (lane>>4)*8 + j][n = lane&15]
//   C/D   : lane holds D[row = (lane>>4)*4 + r][col = lane&15], r=0..3
// h/x LDS layout is FRAG-LINEAR: element (k,n) at half-index
//   (k>>5)*512 + ((k>>3)&3)*128 + n*8 + (k&7)
// -> B-frag k-slice ks = one conflict-free ds_read_b128 at ks*512 + lane*8.
// Write slot for unit u = 32*w + rt*16 + quad*4 + r, col n=ln:
//   w*512 + rt*256 + (quad>>1)*128 + ln*8 + (quad&1)*4   (v4h, r contiguous)
//
// Sync: NO barriers in the main loop. 4-slot rings + LDS flags.
//   flags[0..3] = producer wave p finished step (flag-1); flags[4..7] consumers.
//   producer step t: needs min(fP) >= t   (h0(t-1) ready)
//                    and  min(fC) >= t-3  (slot t&3 = h0(t-4) fully consumed)
//   consumer step t: needs min(fP) >= t+1 (h0(t) ready)
//                    and  min(fC) >= t    (h1(t-1) ready; covers ring reuse)
__global__ __launch_bounds__(NT, 2)
void rnn_pc(const float* __restrict__ x,
            const float* __restrict__ W_ih0, const float* __restrict__ W_hh0,
            const float* __restrict__ b_ih0, const float* __restrict__ b_hh0,
            const float* __restrict__ W_ih1, const float* __restrict__ W_hh1,
            const float* __restrict__ b_ih1, const float* __restrict__ b_hh1,
            const float* __restrict__ fc_w, const float* __restrict__ fc_b,
            float* __restrict__ out)
{
    __shared__ half_t h0r[4][NG][2048];   // 32 KB ring: h0(t) in slot t&3
    __shared__ half_t h1r[4][NG][2048];   // 32 KB ring: h1(t) in slot t&3
    __shared__ half_t xs[TSZ][NG][512];   // 56 KB, frag-linear per (t, group)
    __shared__ int    flags[8];

    const int tid  = threadIdx.x;
    const int wave = tid >> 6;
    const int lane = tid & 63;
    const int ln   = lane & 15;
    const int quad = lane >> 4;
    const int b0   = blockIdx.x * BT;
    const int w4   = wave & 3;            // index within role group
    const int wsl  = w4 * 512 + (quad >> 1) * 128 + ln * 8 + (quad & 1) * 4;
    const int ro   = lane * 8;
    volatile int* vf = (volatile int*)flags;

    // ---- stage ALL x as f16 frag-linear: 3584 chunks = 512 x 7 exactly ----
    // chunk c: q=c&3 (k-quad), n=(c>>2)&15, g=(c>>6)&1, t=c>>7
    {
#pragma unroll
        for (int it = 0; it < 7; ++it) {
            const int c = tid + it * NT;
            const int q = c & 3;
            const int n = (c >> 2) & 15;
            const int g = (c >> 6) & 1;
            const int t = c >> 7;
            const float* gp = x + ((size_t)(b0 + g * 16 + n) * TSZ + t) * ISZ + q * 8;
            float4 a = *(const float4*)gp;
            float4 b = (q < 3) ? *(const float4*)(gp + 4) : make_float4(0.f, 0.f, 0.f, 0.f);
            v8h p = {(half_t)a.x, (half_t)a.y, (half_t)a.z, (half_t)a.w,
                     (half_t)b.x, (half_t)b.y, (half_t)b.z, (half_t)b.w};
            *(v8h*)&xs[t][g][(q * 16 + n) * 8] = p;
        }
    }
    // zero slot 3 of both rings (holds h(-1)); init flags
    {
        const v8h z = {(half_t)0.f, (half_t)0.f, (half_t)0.f, (half_t)0.f,
                       (half_t)0.f, (half_t)0.f, (half_t)0.f, (half_t)0.f};
        *(v8h*)&h0r[3][0][tid * 8] = z;   // flat [NG][2048] = 4096 halves
        *(v8h*)&h1r[3][0][tid * 8] = z;
        if (tid < 8) flags[tid] = 0;
    }
    __syncthreads();

    if (wave < 4) {
        // ================= PRODUCER: layer-0 recurrence =================
        v8h aWx[2], aW0[2][4];
        v4f bias0[2];
#pragma unroll
        for (int rt = 0; rt < 2; ++rt) {
            const int row = w4 * 32 + rt * 16 + ln;
            float4 p = *(const float4*)(b_ih0 + w4 * 32 + rt * 16 + quad * 4);
            float4 q = *(const float4*)(b_hh0 + w4 * 32 + rt * 16 + quad * 4);
            bias0[rt] = (v4f){p.x + q.x, p.y + q.y, p.z + q.z, p.w + q.w};
            const float* pw = W_ih0 + row * ISZ + quad * 8;
            float4 a = *(const float4*)pw;
            float4 b = (quad < 3) ? *(const float4*)(pw + 4) : make_float4(0.f, 0.f, 0.f, 0.f);
            aWx[rt] = (v8h){(half_t)a.x, (half_t)a.y, (half_t)a.z, (half_t)a.w,
                            (half_t)b.x, (half_t)b.y, (half_t)b.z, (half_t)b.w};
#pragma unroll
            for (int ks = 0; ks < 4; ++ks) {
                const float4* p0 = (const float4*)(W_hh0 + row * HSZ + ks * 32 + quad * 8);
                float4 c = p0[0], d = p0[1];
                aW0[rt][ks] = (v8h){(half_t)c.x, (half_t)c.y, (half_t)c.z, (half_t)c.w,
                                    (half_t)d.x, (half_t)d.y, (half_t)d.z, (half_t)d.w};
            }
        }

        for (int t = 0; t < TSZ; ++t) {
            for (;;) {
                int m0 = imin(imin(vf[0], vf[1]), imin(vf[2], vf[3]));
                int m1 = imin(imin(vf[4], vf[5]), imin(vf[6], vf[7]));
                if (m0 >= t && m1 >= t - 3) break;
            }
            __asm__ volatile("" ::: "memory");
            const int sr = (t + 3) & 3, sw = t & 3;
#pragma unroll
            for (int g = 0; g < NG; ++g) {
                v8h bh[4];
#pragma unroll
                for (int ks = 0; ks < 4; ++ks)
                    bh[ks] = *(const v8h*)&h0r[sr][g][ks * 512 + ro];
                const v8h bx = *(const v8h*)&xs[t][g][ro];
#pragma unroll
                for (int rt = 0; rt < 2; ++rt) {
                    v4f c = bias0[rt];
                    c = __builtin_amdgcn_mfma_f32_16x16x32_f16(aWx[rt], bx, c, 0, 0, 0);
#pragma unroll
                    for (int ks = 0; ks < 4; ++ks)
                        c = __builtin_amdgcn_mfma_f32_16x16x32_f16(aW0[rt][ks], bh[ks], c, 0, 0, 0);
                    v4h p = {(half_t)fast_tanh(c[0]), (half_t)fast_tanh(c[1]),
                             (half_t)fast_tanh(c[2]), (half_t)fast_tanh(c[3])};
                    *(v4h*)&h0r[sw][g][wsl + rt * 256] = p;
                }
            }
            __asm__ volatile("s_waitcnt lgkmcnt(0)" ::: "memory");
            if (lane == 0) vf[w4] = t + 1;
        }
    } else {
        // ================= CONSUMER: layer-1 recurrence =================
        v8h aW1i[2][4], aW1h[2][4];
        v4f bias1[2];
#pragma unroll
        for (int rt = 0; rt < 2; ++rt) {
            const int row = w4 * 32 + rt * 16 + ln;
            float4 p = *(const float4*)(b_ih1 + w4 * 32 + rt * 16 + quad * 4);
            float4 q = *(const float4*)(b_hh1 + w4 * 32 + rt * 16 + quad * 4);
            bias1[rt] = (v4f){p.x + q.x, p.y + q.y, p.z + q.z, p.w + q.w};
#pragma unroll
            for (int ks = 0; ks < 4; ++ks) {
                const float4* p1 = (const float4*)(W_ih1 + row * HSZ + ks * 32 + quad * 8);
                const float4* p2 = (const float4*)(W_hh1 + row * HSZ + ks * 32 + quad * 8);
                float4 a = p1[0], b = p1[1];
                aW1i[rt][ks] = (v8h){(half_t)a.x, (half_t)a.y, (half_t)a.z, (half_t)a.w,
                                     (half_t)b.x, (half_t)b.y, (half_t)b.z, (half_t)b.w};
                a = p2[0]; b = p2[1];
                aW1h[rt][ks] = (v8h){(half_t)a.x, (half_t)a.y, (half_t)a.z, (half_t)a.w,
                                     (half_t)b.x, (half_t)b.y, (half_t)b.z, (half_t)b.w};
            }
        }

        for (int t = 0; t < TSZ; ++t) {
            for (;;) {
                int m0 = imin(imin(vf[0], vf[1]), imin(vf[2], vf[3]));
                int m1 = imin(imin(vf[4], vf[5]), imin(vf[6], vf[7]));
                if (m0 >= t + 1 && m1 >= t) break;
            }
            __asm__ volatile("" ::: "memory");
            const int s0 = t & 3, s1 = (t + 3) & 3;
#pragma unroll
            for (int g = 0; g < NG; ++g) {
                v8h bh0[4], bh1[4];
#pragma unroll
                for (int ks = 0; ks < 4; ++ks) {
                    bh0[ks] = *(const v8h*)&h0r[s0][g][ks * 512 + ro];
                    bh1[ks] = *(const v8h*)&h1r[s1][g][ks * 512 + ro];
                }
#pragma unroll
                for (int rt = 0; rt < 2; ++rt) {
                    v4f si = bias1[rt];
                    v4f sh = (v4f){0.f, 0.f, 0.f, 0.f};
#pragma unroll
                    for (int ks = 0; ks < 4; ++ks) {
                        si = __builtin_amdgcn_mfma_f32_16x16x32_f16(aW1i[rt][ks], bh0[ks], si, 0, 0, 0);
                        sh = __builtin_amdgcn_mfma_f32_16x16x32_f16(aW1h[rt][ks], bh1[ks], sh, 0, 0, 0);
                    }
                    const v4f a1 = si + sh;
                    v4h p = {(half_t)fast_tanh(a1[0]), (half_t)fast_tanh(a1[1]),
                             (half_t)fast_tanh(a1[2]), (half_t)fast_tanh(a1[3])};
                    *(v4h*)&h1r[s0][g][wsl + rt * 256] = p;
                }
            }
            __asm__ volatile("s_waitcnt lgkmcnt(0)" ::: "memory");
            if (lane == 0) vf[4 + w4] = t + 1;
        }
    }
    __syncthreads();

    // ---- FC epilogue: out = h1(27) @ fc_w^T + fc_b;  h1(27) in slot 27&3=3 ----
    if (tid < BT * CSZ) {
        const int m = tid / CSZ, cc = tid - m * CSZ;
        const int g = m >> 4, n = m & 15;
        float s = fc_b[cc];
#pragma unroll
        for (int ks = 0; ks < 4; ++ks) {
#pragma unroll
            for (int q2 = 0; q2 < 4; ++q2) {
                const v8h hv = *(const v8h*)&h1r[3][g][(ks * 64 + q2 * 16 + n) * 8];
                const int kb = ks * 32 + q2 * 8;
                const float4 w0 = *(const float4*)(fc_w + cc * HSZ + kb);
                const float4 w1 = *(const float4*)(fc_w + cc * HSZ + kb + 4);
                s += (float)hv[0] * w0.x + (float)hv[1] * w0.y +
                     (float)hv[2] * w0.z + (float)hv[3] * w0.w +
                     (float)hv[4] * w1.x + (float)hv[5] * w1.y +
                     (float)hv[6] * w1.z + (float)hv[7] * w1.w;
            }
        }
        out[(b0 + m) * CSZ + cc] = s;
    }
}

extern "C" void kernel_launch(void* const* d_in, const int* in_sizes, int n_in,
                              void* d_out, int out_size, void* d_ws, size_t ws_size,
                              hipStream_t stream) {
    const float* x     = (const float*)d_in[0];
    const float* W_ih0 = (const float*)d_in[1];
    const float* W_hh0 = (const float*)d_in[2];
    const float* b_ih0 = (const float*)d_in[3];
    const float* b_hh0 = (const float*)d_in[4];
    const float* W_ih1 = (const float*)d_in[5];
    const float* W_hh1 = (const float*)d_in[6];
    const float* b_ih1 = (const float*)d_in[7];
    const float* b_hh1 = (const float*)d_in[8];
    const float* fc_w  = (const float*)d_in[9];
    const float* fc_b  = (const float*)d_in[10];
    float* out = (float*)d_out;

    const int B = in_sizes[0] / (TSZ * ISZ);   // 8192
    dim3 grid(B / BT), block(NT);
    rnn_pc<<<grid, block, 0, stream>>>(x, W_ih0, W_hh0, b_ih0, b_hh0,
                                       W_ih1, W_hh1, b_ih1, b_hh1,
                                       fc_w, fc_b, out);
}